// Round 1
// baseline (11872.195 us; speedup 1.0000x reference)
//
#include <hip/hip_runtime.h>
#include <math.h>

#define RI __restrict__

namespace {

constexpr int Hn = 512, En = 512, Vn = 10000, Fn = 1280, Pn = 196, Bn = 32, Tn = 80;
constexpr int NVT = 157;             // v-tiles of 64 (last tile has 16 valid)

// workspace layout (floats)
constexpr long O_ENC  = 0;                              // [B][P][H] enc_proj
constexpr long O_W2T  = O_ENC + (long)Bn*Pn*Hn;         // [F][H]  W2^T
constexpr long O_H    = O_W2T + (long)Fn*Hn;            // [B][H]  h
constexpr long O_C    = O_H   + (long)Bn*Hn;            // [B][H]  c
constexpr long O_GATE = O_C   + (long)Bn*Hn;            // [B][F]  sigmoid gate
constexpr long O_CTX  = O_GATE+ (long)Bn*Fn;            // [B][F]  raw context
constexpr long O_XP   = O_CTX + (long)Bn*Fn;            // [B][4H] Whh*h + bih + bhh
constexpr long O_PMV  = O_XP  + (long)Bn*4*Hn;          // [B][NVT] partial argmax val
constexpr long O_PMI  = O_PMV + (long)Bn*NVT;           // [B][NVT] partial argmax idx (int)

__device__ __forceinline__ float sigm(float x){ return 1.0f/(1.0f+expf(-x)); }

// ---------------- setup: mean_enc -> h0, c0 ----------------
__global__ __launch_bounds__(256) void k_init(const float* RI feat,
    const float* RI ihw, const float* RI ihb, const float* RI icw, const float* RI icb,
    float* RI ws)
{
  __shared__ float mean[Fn];
  int b = blockIdx.x, tid = threadIdx.x;
  for (int f = tid; f < Fn; f += 256){
    const float* fp = feat + (long)b*Pn*Fn + f;
    float s = 0.f;
    for (int p = 0; p < Pn; ++p) s += fp[(long)p*Fn];
    mean[f] = s * (1.0f/Pn);
  }
  __syncthreads();
  for (int j = tid; j < Hn; j += 256){
    const float* wh = ihw + (long)j*Fn;
    const float* wc = icw + (long)j*Fn;
    float ah = ihb[j], ac = icb[j];
    for (int f = 0; f < Fn; f += 4){
      float4 w1 = *(const float4*)(wh+f);
      float4 w2 = *(const float4*)(wc+f);
      float m0=mean[f], m1=mean[f+1], m2=mean[f+2], m3=mean[f+3];
      ah += w1.x*m0 + w1.y*m1 + w1.z*m2 + w1.w*m3;
      ac += w2.x*m0 + w2.y*m1 + w2.z*m2 + w2.w*m3;
    }
    ws[O_H + (long)b*Hn + j] = ah;
    ws[O_C + (long)b*Hn + j] = ac;
  }
}

// ---------------- transpose W2 ----------------
__global__ __launch_bounds__(256) void k_w2t(const float* RI w2, float* RI ws){
  int gid = blockIdx.x*256 + threadIdx.x;   // = f*512 + h  (grid covers F*H exactly)
  int f = gid >> 9, h = gid & 511;
  ws[O_W2T + gid] = w2[(long)h*Fn + f];
}

// ---------------- enc_proj = feat @ W2^T + b : tiled fp32 GEMM ----------------
// M = B*P = 6272 rows, N = H = 512, K = F = 1280. 64x64 tiles, k-tile 16.
__global__ __launch_bounds__(256) void k_encproj(const float* RI feat, const float* RI w2b,
                                                 float* RI ws)
{
  __shared__ float As[64][17];
  __shared__ float Bs[16][65];
  const float* W2t = ws + O_W2T;
  float* enc = ws + O_ENC;
  int rt = blockIdx.x >> 3, ct = blockIdx.x & 7;
  int r0 = rt*64, j0 = ct*64;
  int tid = threadIdx.x;
  int tx = tid & 15, ty = tid >> 4;
  float acc[4][4] = {};
  for (int k0 = 0; k0 < Fn; k0 += 16){
    for (int i = tid; i < 64*16; i += 256){
      int ar = i >> 4, ak = i & 15;
      As[ar][ak] = feat[(long)(r0+ar)*Fn + k0+ak];
    }
    for (int i = tid; i < 16*64; i += 256){
      int bk = i >> 6, bc = i & 63;
      Bs[bk][bc] = W2t[(long)(k0+bk)*Hn + j0+bc];
    }
    __syncthreads();
    #pragma unroll
    for (int kk = 0; kk < 16; ++kk){
      float a0=As[ty*4+0][kk], a1=As[ty*4+1][kk], a2=As[ty*4+2][kk], a3=As[ty*4+3][kk];
      float b0=Bs[kk][tx*4+0], b1=Bs[kk][tx*4+1], b2=Bs[kk][tx*4+2], b3=Bs[kk][tx*4+3];
      acc[0][0]+=a0*b0; acc[0][1]+=a0*b1; acc[0][2]+=a0*b2; acc[0][3]+=a0*b3;
      acc[1][0]+=a1*b0; acc[1][1]+=a1*b1; acc[1][2]+=a1*b2; acc[1][3]+=a1*b3;
      acc[2][0]+=a2*b0; acc[2][1]+=a2*b1; acc[2][2]+=a2*b2; acc[2][3]+=a2*b3;
      acc[3][0]+=a3*b0; acc[3][1]+=a3*b1; acc[3][2]+=a3*b2; acc[3][3]+=a3*b3;
    }
    __syncthreads();
  }
  for (int i = 0; i < 4; ++i){
    long r = r0 + ty*4 + i;
    for (int j = 0; j < 4; ++j)
      enc[r*Hn + j0 + tx*4 + j] = acc[i][j] + w2b[j0 + tx*4 + j];
  }
}

// ---------------- phase A: everything that depends only on h_t ----------------
// blocks [0,32)    : attention for b (hid, scores, softmax, context)  [t < T]
// blocks [32,448)  : gate = sigm(h@gate_w^T+b), xpart = h@Whh^T+bih+bhh [t < T]
// blocks [448,762) : logits_{t-1} = h_t@out_w^T + out_b, + partial argmax [t >= 1]
// blocks [762,764) : final h,c copy to d_out [t == T]
__global__ __launch_bounds__(256) void k_A(
    const float* RI feat, const float* RI w1w, const float* RI w1b,
    const float* RI vaw, const float* RI vab,
    const float* RI whh, const float* RI bih, const float* RI bhh,
    const float* RI outw, const float* RI outb,
    const float* RI gw, const float* RI gb,
    float* RI ws, float* RI dout, int t)
{
  __shared__ float sm[10240];
  const int bb = blockIdx.x, tid = threadIdx.x;
  const float* hW = ws + O_H;

  if (bb < 32){                       // ---------- attention for b = bb ----------
    if (t >= Tn) return;
    int b = bb;
    float* hl   = sm;         // 512
    float* hidl = sm + 512;   // 512
    float* va   = sm + 1024;  // 512
    float* sc   = sm + 1536;  // 256 (scores, then weights)
    float* red  = sm + 1792;  // 256
    for (int k = tid; k < Hn; k += 256){ hl[k] = hW[(long)b*Hn + k]; va[k] = vaw[k]; }
    __syncthreads();
    for (int j = tid; j < Hn; j += 256){
      const float* wr = w1w + (long)j*Hn;
      float a = w1b[j];
      for (int k = 0; k < Hn; k += 4){
        float4 w = *(const float4*)(wr+k);
        a += w.x*hl[k] + w.y*hl[k+1] + w.z*hl[k+2] + w.w*hl[k+3];
      }
      hidl[j] = a;
    }
    __syncthreads();
    float sval = -1e30f;
    if (tid < Pn){
      const float* er = ws + O_ENC + ((long)b*Pn + tid)*Hn;
      float a = vab[0];
      for (int k = 0; k < Hn; k += 4){
        float4 e4 = *(const float4*)(er+k);
        float r0 = fmaxf(hidl[k+0]+e4.x, 0.f);
        float r1 = fmaxf(hidl[k+1]+e4.y, 0.f);
        float r2 = fmaxf(hidl[k+2]+e4.z, 0.f);
        float r3 = fmaxf(hidl[k+3]+e4.w, 0.f);
        a += va[k]*r0 + va[k+1]*r1 + va[k+2]*r2 + va[k+3]*r3;
      }
      sval = a;
    }
    red[tid] = sval;
    __syncthreads();
    for (int s = 128; s > 0; s >>= 1){ if (tid < s) red[tid] = fmaxf(red[tid], red[tid+s]); __syncthreads(); }
    float mx = red[0];
    __syncthreads();
    float ev = (tid < Pn) ? expf(sval - mx) : 0.f;
    red[tid] = ev;
    __syncthreads();
    for (int s = 128; s > 0; s >>= 1){ if (tid < s) red[tid] += red[tid+s]; __syncthreads(); }
    float wv = ev * (1.0f/red[0]);
    sc[tid] = wv;
    if (tid < Pn)
      dout[(long)Bn*Tn*Vn + 2L*Bn*Hn + ((long)b*Tn + t)*Pn + tid] = wv;
    __syncthreads();
    // context (raw, gate applied later)
    for (int fq = tid; fq < Fn/4; fq += 256){
      int f = fq*4;
      const float* fp = feat + (long)b*Pn*Fn + f;
      float a0=0,a1=0,a2=0,a3=0;
      for (int p = 0; p < Pn; ++p){
        float wp = sc[p];
        float4 v4 = *(const float4*)(fp + (long)p*Fn);
        a0 += wp*v4.x; a1 += wp*v4.y; a2 += wp*v4.z; a3 += wp*v4.w;
      }
      float* cx = ws + O_CTX + (long)b*Fn + f;
      cx[0]=a0; cx[1]=a1; cx[2]=a2; cx[3]=a3;
    }

  } else if (bb < 448){               // ---------- gate + xpart ----------
    if (t >= Tn) return;
    int idx = (bb-32)*256 + tid;      // 416*256 = 106496 = B*F + B*4H exactly
    if (idx < Bn*Fn){
      int b = idx / Fn, f = idx - b*Fn;
      const float* wr = gw + (long)f*Hn;
      const float* hb = hW + (long)b*Hn;
      float a = gb[f];
      for (int k = 0; k < Hn; k += 4){
        float4 w = *(const float4*)(wr+k);
        float4 h4 = *(const float4*)(hb+k);
        a += w.x*h4.x + w.y*h4.y + w.z*h4.z + w.w*h4.w;
      }
      ws[O_GATE + idx] = sigm(a);
    } else {
      int j2 = idx - Bn*Fn;
      int b = j2 >> 11, j = j2 & 2047;
      const float* wr = whh + (long)j*Hn;
      const float* hb = hW + (long)b*Hn;
      float a = bih[j] + bhh[j];
      for (int k = 0; k < Hn; k += 4){
        float4 w = *(const float4*)(wr+k);
        float4 h4 = *(const float4*)(hb+k);
        a += w.x*h4.x + w.y*h4.y + w.z*h4.z + w.w*h4.w;
      }
      ws[O_XP + j2] = a;
    }

  } else if (bb < 762){               // ---------- logits_{t-1} + partial argmax ----------
    if (t == 0) return;
    int lu = bb - 448;                // 0..313
    int vt = lu >> 1, bh = lu & 1;
    int v0 = vt*64, b0 = bh*16;
    float* hT = sm;                   // [512][16]
    float* rv = sm + 8192;            // [16][64]
    for (int i = tid; i < 8192; i += 256){
      int k = i >> 4, bl = i & 15;
      hT[i] = hW[(long)(b0+bl)*Hn + k];
    }
    __syncthreads();
    int vl = tid & 63, bq = tid >> 6;
    int v = v0 + vl;
    float a0=0,a1=0,a2=0,a3=0;
    if (v < Vn){
      const float* wr = outw + (long)v*Hn;
      for (int k = 0; k < Hn; k += 4){
        float4 w  = *(const float4*)(wr + k);
        float4 x0 = *(const float4*)(hT + (k+0)*16 + bq*4);
        float4 x1 = *(const float4*)(hT + (k+1)*16 + bq*4);
        float4 x2 = *(const float4*)(hT + (k+2)*16 + bq*4);
        float4 x3 = *(const float4*)(hT + (k+3)*16 + bq*4);
        a0 += w.x*x0.x + w.y*x1.x + w.z*x2.x + w.w*x3.x;
        a1 += w.x*x0.y + w.y*x1.y + w.z*x2.y + w.w*x3.y;
        a2 += w.x*x0.z + w.y*x1.z + w.z*x2.z + w.w*x3.z;
        a3 += w.x*x0.w + w.y*x1.w + w.z*x2.w + w.w*x3.w;
      }
    }
    float l0=-1e30f, l1=-1e30f, l2=-1e30f, l3=-1e30f;
    if (v < Vn){
      float bias = outb[v];
      l0 = a0+bias; l1 = a1+bias; l2 = a2+bias; l3 = a3+bias;
      long tb = (long)(t-1)*Vn + v;
      dout[(long)(b0+bq*4+0)*Tn*Vn + tb] = l0;
      dout[(long)(b0+bq*4+1)*Tn*Vn + tb] = l1;
      dout[(long)(b0+bq*4+2)*Tn*Vn + tb] = l2;
      dout[(long)(b0+bq*4+3)*Tn*Vn + tb] = l3;
    }
    rv[(bq*4+0)*64 + vl] = l0;
    rv[(bq*4+1)*64 + vl] = l1;
    rv[(bq*4+2)*64 + vl] = l2;
    rv[(bq*4+3)*64 + vl] = l3;
    __syncthreads();
    int bl = tid >> 4, e = tid & 15;
    float bv = -1e30f; int bi = 0;
    #pragma unroll
    for (int q = 0; q < 4; ++q){
      int vv = e + q*16;                          // ascending -> first-max tie-break
      float cv = rv[bl*64 + vv];
      if (cv > bv){ bv = cv; bi = vv; }
    }
    for (int off = 8; off; off >>= 1){
      float ov = __shfl_down(bv, off, 16);
      int   oi = __shfl_down(bi, off, 16);
      if (ov > bv || (ov == bv && oi < bi)){ bv = ov; bi = oi; }
    }
    if (e == 0){
      ws[O_PMV + (long)(b0+bl)*NVT + vt] = bv;
      ((int*)(ws + O_PMI))[(long)(b0+bl)*NVT + vt] = v0 + bi;
    }

  } else {                            // ---------- final h,c copy ----------
    if (t != Tn) return;
    int g = bb - 762;                 // 0 = h, 1 = c
    const float* src = ws + (g == 0 ? O_H : O_C);
    float* dst = dout + (long)Bn*Tn*Vn + (long)g*Bn*Hn;
    for (int i = tid; i < Bn*Hn; i += 256) dst[i] = src[i];
  }
}

// ---------------- phase B: argmax finalize + LSTM gates + state update ----------------
// 256 blocks = 64 i-groups (8 hidden each) x 4 b-groups (8 batch each)
__global__ __launch_bounds__(256) void k_B(const float* RI emb, const float* RI wih,
                                           float* RI ws, int t)
{
  __shared__ float xT[1792*8];    // x^T staged [k][bl]   (57,344 B)
  __shared__ float gl[32*8];
  __shared__ int amax_s[8];
  const int bb = blockIdx.x, tid = threadIdx.x;
  const int ig = bb >> 2, bg = bb & 3;
  const int i0 = ig*8, b0 = bg*8;

  if (t > 0){                      // finalize argmax for this block's 8 batches
    int bl = tid >> 5, e = tid & 31;
    int b = b0 + bl;
    float bv = -1e30f; int bi = 0x7fffffff;
    for (int q = e; q < NVT; q += 32){
      float cv = ws[O_PMV + (long)b*NVT + q];
      if (cv > bv){ bv = cv; bi = ((const int*)(ws + O_PMI))[(long)b*NVT + q]; }
    }
    for (int off = 16; off; off >>= 1){
      float ov = __shfl_down(bv, off, 32);
      int   oi = __shfl_down(bi, off, 32);
      if (ov > bv || (ov == bv && oi < bi)){ bv = ov; bi = oi; }
    }
    if (e == 0) amax_s[bl] = bi;
  }
  __syncthreads();

  // stage x^T = [embedding row | ctx*gate] for 8 batches
  for (int i = tid; i < 1792*8; i += 256){
    int k = i >> 3, bl = i & 7;
    float x;
    if (k < En){
      int row = (t == 0) ? 1 : amax_s[bl];        // SOS = 1
      x = emb[(long)row*En + k];
    } else {
      int f = k - En, b = b0 + bl;
      x = ws[O_CTX + (long)b*Fn + f] * ws[O_GATE + (long)b*Fn + f];
    }
    xT[i] = x;
  }
  __syncthreads();

  const int jl = tid & 31, kq = tid >> 5;
  const int quad = jl >> 3, il = jl & 7;
  const int j = quad*Hn + i0 + il;
  const float* wr = wih + (long)j*1792 + kq*224;
  const float* xp = xT + kq*224*8;
  float a0=0,a1=0,a2=0,a3=0,a4=0,a5=0,a6=0,a7=0;
  for (int k = 0; k < 224; k += 4){
    float4 w = *(const float4*)(wr + k);
    {
      float4 xa = *(const float4*)(xp + (k+0)*8);
      float4 xb = *(const float4*)(xp + (k+0)*8 + 4);
      a0+=w.x*xa.x; a1+=w.x*xa.y; a2+=w.x*xa.z; a3+=w.x*xa.w;
      a4+=w.x*xb.x; a5+=w.x*xb.y; a6+=w.x*xb.z; a7+=w.x*xb.w;
    }{
      float4 xa = *(const float4*)(xp + (k+1)*8);
      float4 xb = *(const float4*)(xp + (k+1)*8 + 4);
      a0+=w.y*xa.x; a1+=w.y*xa.y; a2+=w.y*xa.z; a3+=w.y*xa.w;
      a4+=w.y*xb.x; a5+=w.y*xb.y; a6+=w.y*xb.z; a7+=w.y*xb.w;
    }{
      float4 xa = *(const float4*)(xp + (k+2)*8);
      float4 xb = *(const float4*)(xp + (k+2)*8 + 4);
      a0+=w.z*xa.x; a1+=w.z*xa.y; a2+=w.z*xa.z; a3+=w.z*xa.w;
      a4+=w.z*xb.x; a5+=w.z*xb.y; a6+=w.z*xb.z; a7+=w.z*xb.w;
    }{
      float4 xa = *(const float4*)(xp + (k+3)*8);
      float4 xb = *(const float4*)(xp + (k+3)*8 + 4);
      a0+=w.w*xa.x; a1+=w.w*xa.y; a2+=w.w*xa.z; a3+=w.w*xa.w;
      a4+=w.w*xb.x; a5+=w.w*xb.y; a6+=w.w*xb.z; a7+=w.w*xb.w;
    }
  }
  __syncthreads();
  float* pb = xT;                  // alias: [32 jl][8 bl][8 kq]
  pb[(jl*8+0)*8+kq]=a0; pb[(jl*8+1)*8+kq]=a1; pb[(jl*8+2)*8+kq]=a2; pb[(jl*8+3)*8+kq]=a3;
  pb[(jl*8+4)*8+kq]=a4; pb[(jl*8+5)*8+kq]=a5; pb[(jl*8+6)*8+kq]=a6; pb[(jl*8+7)*8+kq]=a7;
  __syncthreads();
  {
    int jl2 = tid >> 3, blx = tid & 7;
    float g = 0.f;
    #pragma unroll
    for (int q = 0; q < 8; ++q) g += pb[(jl2*8+blx)*8 + q];
    int quad2 = jl2 >> 3, il2 = jl2 & 7;
    int jj = quad2*Hn + i0 + il2;
    g += ws[O_XP + (long)(b0+blx)*2048 + jj];
    gl[jl2*8 + blx] = g;
  }
  __syncthreads();
  if (tid < 64){
    int il3 = tid >> 3, bl3 = tid & 7;
    int b = b0 + bl3;
    float gi = gl[( 0+il3)*8 + bl3];
    float gf = gl[( 8+il3)*8 + bl3];
    float gg = gl[(16+il3)*8 + bl3];
    float go = gl[(24+il3)*8 + bl3];
    float co = ws[O_C + (long)b*Hn + i0+il3];
    float cn = sigm(gf)*co + sigm(gi)*tanhf(gg);
    float hn = sigm(go)*tanhf(cn);
    ws[O_C + (long)b*Hn + i0+il3] = cn;
    ws[O_H + (long)b*Hn + i0+il3] = hn;
  }
}

} // anonymous namespace

extern "C" void kernel_launch(void* const* d_in, const int* in_sizes, int n_in,
                              void* d_out, int out_size, void* d_ws, size_t ws_size,
                              hipStream_t stream)
{
  const float* feat = (const float*)d_in[0];
  // d_in[1] caption, d_in[2] max_caption: unused (greedy decode, T=80 fixed)
  const float* emb  = (const float*)d_in[3];
  const float* w1w  = (const float*)d_in[4];
  const float* w1b  = (const float*)d_in[5];
  const float* w2w  = (const float*)d_in[6];
  const float* w2b  = (const float*)d_in[7];
  const float* vaw  = (const float*)d_in[8];
  const float* vab  = (const float*)d_in[9];
  const float* wih  = (const float*)d_in[10];
  const float* whh  = (const float*)d_in[11];
  const float* bih  = (const float*)d_in[12];
  const float* bhh  = (const float*)d_in[13];
  const float* outw = (const float*)d_in[14];
  const float* outb = (const float*)d_in[15];
  const float* ihw  = (const float*)d_in[16];
  const float* ihb  = (const float*)d_in[17];
  const float* icw  = (const float*)d_in[18];
  const float* icb  = (const float*)d_in[19];
  const float* gw   = (const float*)d_in[20];
  const float* gb   = (const float*)d_in[21];
  float* ws  = (float*)d_ws;
  float* out = (float*)d_out;

  k_init<<<dim3(32), dim3(256), 0, stream>>>(feat, ihw, ihb, icw, icb, ws);
  k_w2t<<<dim3(2560), dim3(256), 0, stream>>>(w2w, ws);
  k_encproj<<<dim3(784), dim3(256), 0, stream>>>(feat, w2b, ws);

  for (int t = 0; t <= Tn; ++t){
    k_A<<<dim3(764), dim3(256), 0, stream>>>(feat, w1w, w1b, vaw, vab,
                                             whh, bih, bhh, outw, outb, gw, gb,
                                             ws, out, t);
    if (t < Tn)
      k_B<<<dim3(256), dim3(256), 0, stream>>>(emb, wih, ws, t);
  }
}